// Round 5
// baseline (261.993 us; speedup 1.0000x reference)
//
#include <hip/hip_runtime.h>

#define D 128
#define PAD 16

typedef short short8 __attribute__((ext_vector_type(8)));
typedef float f32x4 __attribute__((ext_vector_type(4)));

// round-to-nearest-even f32 -> bf16 bits
__device__ __forceinline__ unsigned int f2bf(float x) {
    unsigned int u = __float_as_uint(x);
    return (u + 0x7fffu + ((u >> 16) & 1u)) >> 16;
}

// ---------------- h f32 -> bf16 (row-major [N][128]) -------------------------
__global__ __launch_bounds__(256) void conv_h_k(const float* __restrict__ h,
                                                unsigned short* __restrict__ hb,
                                                int n8) {
    int i = blockIdx.x * 256 + threadIdx.x;
    if (i >= n8) return;
    const float4* hp = (const float4*)h;
    float4 v0 = hp[2 * i + 0], v1 = hp[2 * i + 1];
    uint4 o;
    o.x = f2bf(v0.x) | (f2bf(v0.y) << 16);
    o.y = f2bf(v0.z) | (f2bf(v0.w) << 16);
    o.z = f2bf(v1.x) | (f2bf(v1.y) << 16);
    o.w = f2bf(v1.z) | (f2bf(v1.w) << 16);
    ((uint4*)hb)[i] = o;
}

// ---------------- W pack: B-fragment order [12][8][64][8] bf16 ---------------
__global__ void pack_w_k(const float* __restrict__ W,
                         unsigned short* __restrict__ Wb) {
    int t = blockIdx.x * 256 + threadIdx.x;
    if (t >= 12 * 8 * 64) return;
    int lane = t & 63, cg = (t >> 6) & 7, kg = t >> 9;
    int col = cg * 16 + (lane & 15);
    int r = kg >> 2;
    int klocal = (kg & 3) * 32 + (lane >> 4) * 8;
    const float* Ws = W + ((size_t)r * D + klocal) * D + col;
    uint4 o;
    o.x = f2bf(Ws[0 * D]) | (f2bf(Ws[1 * D]) << 16);
    o.y = f2bf(Ws[2 * D]) | (f2bf(Ws[3 * D]) << 16);
    o.z = f2bf(Ws[4 * D]) | (f2bf(Ws[5 * D]) << 16);
    o.w = f2bf(Ws[6 * D]) | (f2bf(Ws[7 * D]) << 16);
    ((uint4*)Wb)[t] = o;
}

// ---------------- chain build: one pass, coalesced 8B writes -----------------
__global__ void chain_k(const int* __restrict__ src, const int* __restrict__ dst,
                        int* __restrict__ head, int2* __restrict__ chain,
                        int E, int N, int nbE) {
    int r = blockIdx.x / nbE;
    int i = (blockIdx.x - r * nbE) * 256 + threadIdx.x;
    if (i >= E) return;
    size_t gi = (size_t)r * E + i;
    int d = dst[gi];
    int s = src[gi];
    int old = atomicExch(&head[r * N + d], (int)gi);
    chain[gi] = make_int2(s, old);
}

// ---------------- flatten: chain -> padded CSR (one thread per (r,node)) -----
// csr[rn*PAD + j] = src ids (first PAD); deg[rn] = full degree.
__global__ void flat_k(const int* __restrict__ head,
                       const int2* __restrict__ chain, int* __restrict__ csr,
                       int* __restrict__ deg, int RN) {
    int rn = blockIdx.x * 256 + threadIdx.x;
    if (rn >= RN) return;
    int e = head[rn];
    int d = 0;
    int* cp = csr + (size_t)rn * PAD;
    while (e >= 0) {
        int2 ce = chain[e];
        if (d < PAD) cp[d] = ce.x;
        ++d;
        e = ce.y;
    }
    deg[rn] = d;
}

// ---------------- agg: segment-mean of h rows, A-fragment-packed -------------
// Block = 256 threads = one 16-node row group of one relation.
// Thread t: node = grp*16 + (lane&15), features c = kgl*32 + (lane>>4)*8 .. +7.
#define GATHER_ADD(sidx)                                                     \
    {                                                                        \
        uint4 u = *(const uint4*)(hb + ((size_t)(sidx) << 7) + c);           \
        a0 += __uint_as_float(u.x << 16);                                    \
        a1 += __uint_as_float(u.x & 0xffff0000u);                            \
        a2 += __uint_as_float(u.y << 16);                                    \
        a3 += __uint_as_float(u.y & 0xffff0000u);                            \
        a4 += __uint_as_float(u.z << 16);                                    \
        a5 += __uint_as_float(u.z & 0xffff0000u);                            \
        a6 += __uint_as_float(u.w << 16);                                    \
        a7 += __uint_as_float(u.w & 0xffff0000u);                            \
    }

__global__ __launch_bounds__(256) void agg_k(
    const unsigned short* __restrict__ hb, const int* __restrict__ csr,
    const int* __restrict__ deg, const int* __restrict__ head,
    const int2* __restrict__ chain, unsigned short* __restrict__ A,
    int N, int NG, int KS, int kgbPerR, int r0, int useCsr) {
    int r = r0 + blockIdx.x / NG;
    int grp = blockIdx.x % NG;
    int lane = threadIdx.x & 63;
    int kgl = threadIdx.x >> 6;
    int n = grp * 16 + (lane & 15);
    if (n >= N) n = N - 1;
    int rn = r * N + n;
    int c = kgl * 32 + (lane >> 4) * 8;
    float a0 = 0, a1 = 0, a2 = 0, a3 = 0, a4 = 0, a5 = 0, a6 = 0, a7 = 0;
    int cntE = 0;
    if (useCsr) {
        cntE = deg[rn];
        if (cntE <= PAD) {
            const int* cp = csr + (size_t)rn * PAD;
            for (int j = 0; j < cntE; ++j) {
                int s = cp[j];
                GATHER_ADD(s);
            }
        } else {  // rare overflow: full chain walk
            int e = head[rn];
            while (e >= 0) {
                int2 ce = chain[e];
                GATHER_ADD(ce.x);
                e = ce.y;
            }
        }
    } else {
        int e = head[rn];
        while (e >= 0) {
            int2 ce = chain[e];
            ++cntE;
            GATHER_ADD(ce.x);
            e = ce.y;
        }
    }
    float sc = 1.0f / (3.0f * fmaxf((float)cntE, 1.0f));
    uint4 o;
    o.x = f2bf(a0 * sc) | (f2bf(a1 * sc) << 16);
    o.y = f2bf(a2 * sc) | (f2bf(a3 * sc) << 16);
    o.z = f2bf(a4 * sc) | (f2bf(a5 * sc) << 16);
    o.w = f2bf(a6 * sc) | (f2bf(a7 * sc) << 16);
    ((uint4*)A)[((size_t)grp * KS + kgbPerR * r + kgl) * 64 + lane] = o;
}

// ---------------- MFMA GEMM, no LDS, fragments straight from global ----------
// out[row][col] = bf2f(addend_bf16[row][col]) + sum_k A[row][k]*B[k][col]
template <int KG>
__global__ __launch_bounds__(256) void gemm_k(
    const unsigned short* __restrict__ A, const unsigned short* __restrict__ B,
    const unsigned short* __restrict__ addend, const float* __restrict__ addf,
    float* __restrict__ out, int N, int NG, int kgB) {
    int lane = threadIdx.x & 63;
    int w = threadIdx.x >> 6;
    int wr = w >> 1, wc = w & 1;
    int rg0 = blockIdx.x * 8 + wr * 4;
    const short8* Ap = (const short8*)A;
    const short8* Bp = (const short8*)B;
    f32x4 acc[4][4];
#pragma unroll
    for (int m = 0; m < 4; ++m)
#pragma unroll
        for (int n = 0; n < 4; ++n) acc[m][n] = (f32x4){0.f, 0.f, 0.f, 0.f};
#pragma unroll 2
    for (int kg = 0; kg < KG; ++kg) {
        short8 a[4], b[4];
#pragma unroll
        for (int m = 0; m < 4; ++m) {
            int rg = rg0 + m;
            rg = rg < NG ? rg : NG - 1;
            a[m] = Ap[((size_t)rg * KG + kg) * 64 + lane];
        }
#pragma unroll
        for (int n = 0; n < 4; ++n)
            b[n] = Bp[(((size_t)(kgB + kg)) * 8 + wc * 4 + n) * 64 + lane];
#pragma unroll
        for (int m = 0; m < 4; ++m)
#pragma unroll
            for (int n = 0; n < 4; ++n)
                acc[m][n] = __builtin_amdgcn_mfma_f32_16x16x32_bf16(
                    a[m], b[n], acc[m][n], 0, 0, 0);
    }
    // D layout (m89-verified): col = lane&15, row = (lane>>4)*4 + reg
    int col0 = wc * 64 + (lane & 15);
    int rbase = blockIdx.x * 128 + wr * 64 + ((lane >> 4) << 2);
#pragma unroll
    for (int m = 0; m < 4; ++m)
#pragma unroll
        for (int r = 0; r < 4; ++r) {
            int row = rbase + m * 16 + r;
            if (row < N) {
                float* op = out + ((size_t)row << 7) + col0;
                if (addend) {
                    const unsigned short* ap = addend + ((size_t)row << 7) + col0;
#pragma unroll
                    for (int n = 0; n < 4; ++n)
                        op[n * 16] =
                            __uint_as_float((unsigned int)ap[n * 16] << 16) +
                            acc[m][n][r];
                } else {
                    const float* ap = addf + ((size_t)row << 7) + col0;
#pragma unroll
                    for (int n = 0; n < 4; ++n)
                        op[n * 16] = ap[n * 16] + acc[m][n][r];
                }
            }
        }
}

extern "C" void kernel_launch(void* const* d_in, const int* in_sizes, int n_in,
                              void* d_out, int out_size, void* d_ws, size_t ws_size,
                              hipStream_t stream) {
    const float* h = (const float*)d_in[0];
    const float* W = (const float*)d_in[1];
    const int* src = (const int*)d_in[2];
    const int* dst = (const int*)d_in[3];
    float* out = (float*)d_out;

    const int N = in_sizes[0] / D;     // 100000
    const int R = 3;
    const int E = in_sizes[2] / R;     // 500000
    const int RN = R * N;
    const int NG = (N + 15) / 16;      // 6250 row groups
    const int nbE = (E + 255) / 256;

    auto al16 = [](size_t x) { return (x + 15) & ~(size_t)15; };
    size_t sz_hb = al16((size_t)N * D * 2);
    size_t sz_Wb = al16((size_t)12 * 8 * 64 * 8 * 2);
    size_t sz_head = al16((size_t)RN * 4);
    size_t sz_chain = al16((size_t)R * E * 8);
    size_t sz_csr = al16((size_t)RN * PAD * 4);
    size_t sz_deg = al16((size_t)RN * 4);
    size_t sz_A12 = al16((size_t)NG * 12 * 512 * 2);
    size_t sz_A4 = al16((size_t)NG * 4 * 512 * 2);
    size_t baseB = sz_A12 + sz_hb + sz_Wb + sz_head + sz_chain;
    bool tierA = ws_size >= baseB + sz_csr + sz_deg;   // fused + CSR
    bool tierB = !tierA && ws_size >= baseB;           // fused + chain-walk agg
    size_t sz_A = (tierA || tierB) ? sz_A12 : sz_A4;

    char* p = (char*)d_ws;
    unsigned short* A  = (unsigned short*)p; p += sz_A;
    unsigned short* hb = (unsigned short*)p; p += sz_hb;
    unsigned short* Wb = (unsigned short*)p; p += sz_Wb;
    int*  head  = (int*)p;  p += sz_head;
    int2* chain = (int2*)p; p += sz_chain;
    int*  csr = (int*)p;    p += sz_csr;
    int*  deg = (int*)p;    p += sz_deg;

    hipMemsetAsync(head, 0xFF, (size_t)RN * 4, stream);   // head = -1
    conv_h_k<<<(N * D / 8 + 255) / 256, 256, 0, stream>>>(h, hb, N * D / 8);
    pack_w_k<<<(12 * 8 * 64 + 255) / 256, 256, 0, stream>>>(W, Wb);
    chain_k<<<R * nbE, 256, 0, stream>>>(src, dst, head, chain, E, N, nbE);
    if (tierA)
        flat_k<<<(RN + 255) / 256, 256, 0, stream>>>(head, chain, csr, deg, RN);

    int gblk = (NG + 7) / 8;
    int useCsr = tierA ? 1 : 0;
    if (tierA || tierB) {
        agg_k<<<R * NG, 256, 0, stream>>>(hb, csr, deg, head, chain, A,
                                          N, NG, 12, 4, 0, useCsr);
        gemm_k<12><<<gblk, 256, 0, stream>>>(A, Wb, hb, nullptr, out, N, NG, 0);
    } else {
        for (int r = 0; r < R; ++r) {
            agg_k<<<NG, 256, 0, stream>>>(hb, csr, deg, head, chain, A,
                                          N, NG, 4, 0, r, 0);
            gemm_k<4><<<gblk, 256, 0, stream>>>(
                A, Wb, (r == 0) ? hb : nullptr, (r == 0) ? nullptr : out, out,
                N, NG, r * 4);
        }
    }
}

// Round 6
// 246.958 us; speedup vs baseline: 1.0609x; 1.0609x over previous
//
#include <hip/hip_runtime.h>

#define D 128
#define PAD 16

typedef short short8 __attribute__((ext_vector_type(8)));
typedef float f32x4 __attribute__((ext_vector_type(4)));

// round-to-nearest-even f32 -> bf16 bits
__device__ __forceinline__ unsigned int f2bf(float x) {
    unsigned int u = __float_as_uint(x);
    return (u + 0x7fffu + ((u >> 16) & 1u)) >> 16;
}

// ---------------- h f32 -> bf16 (row-major [N][128]) + zero row at N ---------
__global__ __launch_bounds__(256) void conv_h_k(const float* __restrict__ h,
                                                unsigned short* __restrict__ hb,
                                                int n8, int n8tot) {
    int i = blockIdx.x * 256 + threadIdx.x;
    if (i >= n8tot) return;
    if (i >= n8) {  // zero row (gather sink)
        ((uint4*)hb)[i] = make_uint4(0u, 0u, 0u, 0u);
        return;
    }
    const float4* hp = (const float4*)h;
    float4 v0 = hp[2 * i + 0], v1 = hp[2 * i + 1];
    uint4 o;
    o.x = f2bf(v0.x) | (f2bf(v0.y) << 16);
    o.y = f2bf(v0.z) | (f2bf(v0.w) << 16);
    o.z = f2bf(v1.x) | (f2bf(v1.y) << 16);
    o.w = f2bf(v1.z) | (f2bf(v1.w) << 16);
    ((uint4*)hb)[i] = o;
}

// ---------------- W pack: B-fragment order [12][8][64][8] bf16 ---------------
__global__ void pack_w_k(const float* __restrict__ W,
                         unsigned short* __restrict__ Wb) {
    int t = blockIdx.x * 256 + threadIdx.x;
    if (t >= 12 * 8 * 64) return;
    int lane = t & 63, cg = (t >> 6) & 7, kg = t >> 9;
    int col = cg * 16 + (lane & 15);
    int r = kg >> 2;
    int klocal = (kg & 3) * 32 + (lane >> 4) * 8;
    const float* Ws = W + ((size_t)r * D + klocal) * D + col;
    uint4 o;
    o.x = f2bf(Ws[0 * D]) | (f2bf(Ws[1 * D]) << 16);
    o.y = f2bf(Ws[2 * D]) | (f2bf(Ws[3 * D]) << 16);
    o.z = f2bf(Ws[4 * D]) | (f2bf(Ws[5 * D]) << 16);
    o.w = f2bf(Ws[6 * D]) | (f2bf(Ws[7 * D]) << 16);
    ((uint4*)Wb)[t] = o;
}

// ---------------- chain build: one pass, coalesced 8B writes -----------------
__global__ void chain_k(const int* __restrict__ src, const int* __restrict__ dst,
                        int* __restrict__ head, int2* __restrict__ chain,
                        int E, int N, int nbE) {
    int r = blockIdx.x / nbE;
    int i = (blockIdx.x - r * nbE) * 256 + threadIdx.x;
    if (i >= E) return;
    size_t gi = (size_t)r * E + i;
    int d = dst[gi];
    int s = src[gi];
    int old = atomicExch(&head[r * N + d], (int)gi);
    chain[gi] = make_int2(s, old);
}

// ---------------- flatten: chain -> padded CSR (one thread per (r,node)) -----
__global__ void flat_k(const int* __restrict__ head,
                       const int2* __restrict__ chain, int* __restrict__ csr,
                       int* __restrict__ deg, int RN) {
    int rn = blockIdx.x * 256 + threadIdx.x;
    if (rn >= RN) return;
    int e = head[rn];
    int d = 0;
    int* cp = csr + (size_t)rn * PAD;
    while (e >= 0) {
        int2 ce = chain[e];
        if (d < PAD) cp[d] = ce.x;
        ++d;
        e = ce.y;
    }
    deg[rn] = d;
}

// ---------------- agg: segment-mean of h rows, A-fragment-packed -------------
// Block = 256 threads = one 16-node row group of one relation.
// Thread t: node = grp*16 + (lane&15), features c = kgl*32 + (lane>>4)*8 .. +7.
__global__ __launch_bounds__(256) void agg_k(
    const unsigned short* __restrict__ hb, const int* __restrict__ csr,
    const int* __restrict__ deg, const int* __restrict__ head,
    const int2* __restrict__ chain, unsigned short* __restrict__ A,
    int N, int NG, int KS, int kgbPerR, int r0, int useCsr) {
    int r = r0 + blockIdx.x / NG;
    int grp = blockIdx.x % NG;
    int lane = threadIdx.x & 63;
    int kgl = threadIdx.x >> 6;
    int n = grp * 16 + (lane & 15);
    if (n >= N) n = N - 1;
    int rn = r * N + n;
    int c = kgl * 32 + (lane >> 4) * 8;
    float a0 = 0, a1 = 0, a2 = 0, a3 = 0, a4 = 0, a5 = 0, a6 = 0, a7 = 0;
    int cntE = 0;

#define ACC8(u)                                                              \
    {                                                                        \
        a0 += __uint_as_float((u).x << 16);                                  \
        a1 += __uint_as_float((u).x & 0xffff0000u);                          \
        a2 += __uint_as_float((u).y << 16);                                  \
        a3 += __uint_as_float((u).y & 0xffff0000u);                          \
        a4 += __uint_as_float((u).z << 16);                                  \
        a5 += __uint_as_float((u).z & 0xffff0000u);                          \
        a6 += __uint_as_float((u).w << 16);                                  \
        a7 += __uint_as_float((u).w & 0xffff0000u);                          \
    }
#define GLD(s) (*(const uint4*)(hb + ((size_t)(s) << 7) + c))

    if (useCsr) {
        cntE = deg[rn];
        if (cntE <= PAD) {
            const int4* cp4 = (const int4*)(csr + (size_t)rn * PAD);
            if (cntE > 0) {
                int4 iv0 = cp4[0], iv1 = cp4[1];
                int s0 = iv0.x;                       // j=0 valid (cntE>0)
                int s1 = (1 < cntE) ? iv0.y : N;
                int s2 = (2 < cntE) ? iv0.z : N;
                int s3 = (3 < cntE) ? iv0.w : N;
                int s4 = (4 < cntE) ? iv1.x : N;
                int s5 = (5 < cntE) ? iv1.y : N;
                int s6 = (6 < cntE) ? iv1.z : N;
                int s7 = (7 < cntE) ? iv1.w : N;
                uint4 u0 = GLD(s0), u1 = GLD(s1), u2 = GLD(s2), u3 = GLD(s3);
                uint4 u4 = GLD(s4), u5 = GLD(s5), u6 = GLD(s6), u7 = GLD(s7);
                ACC8(u0); ACC8(u1); ACC8(u2); ACC8(u3);
                ACC8(u4); ACC8(u5); ACC8(u6); ACC8(u7);
            }
            if (cntE > 8) {
                int4 iv0 = cp4[2], iv1 = cp4[3];
                int s0 = iv0.x;                       // j=8 valid (cntE>8)
                int s1 = (9 < cntE) ? iv0.y : N;
                int s2 = (10 < cntE) ? iv0.z : N;
                int s3 = (11 < cntE) ? iv0.w : N;
                int s4 = (12 < cntE) ? iv1.x : N;
                int s5 = (13 < cntE) ? iv1.y : N;
                int s6 = (14 < cntE) ? iv1.z : N;
                int s7 = (15 < cntE) ? iv1.w : N;
                uint4 u0 = GLD(s0), u1 = GLD(s1), u2 = GLD(s2), u3 = GLD(s3);
                uint4 u4 = GLD(s4), u5 = GLD(s5), u6 = GLD(s6), u7 = GLD(s7);
                ACC8(u0); ACC8(u1); ACC8(u2); ACC8(u3);
                ACC8(u4); ACC8(u5); ACC8(u6); ACC8(u7);
            }
        } else {  // rare overflow: full chain walk
            int e = head[rn];
            while (e >= 0) {
                int2 ce = chain[e];
                uint4 u = GLD(ce.x);
                ACC8(u);
                e = ce.y;
            }
        }
    } else {
        int e = head[rn];
        while (e >= 0) {
            int2 ce = chain[e];
            ++cntE;
            uint4 u = GLD(ce.x);
            ACC8(u);
            e = ce.y;
        }
    }
    float sc = 1.0f / (3.0f * fmaxf((float)cntE, 1.0f));
    uint4 o;
    o.x = f2bf(a0 * sc) | (f2bf(a1 * sc) << 16);
    o.y = f2bf(a2 * sc) | (f2bf(a3 * sc) << 16);
    o.z = f2bf(a4 * sc) | (f2bf(a5 * sc) << 16);
    o.w = f2bf(a6 * sc) | (f2bf(a7 * sc) << 16);
    ((uint4*)A)[((size_t)grp * KS + kgbPerR * r + kgl) * 64 + lane] = o;
#undef ACC8
#undef GLD
}

// ---------------- MFMA GEMM, no LDS, fragments straight from global ----------
// out[row][col] = bf2f(addend_bf16[row][col]) + sum_k A[row][k]*B[k][col]
template <int KG>
__global__ __launch_bounds__(256) void gemm_k(
    const unsigned short* __restrict__ A, const unsigned short* __restrict__ B,
    const unsigned short* __restrict__ addend, const float* __restrict__ addf,
    float* __restrict__ out, int N, int NG, int kgB) {
    int lane = threadIdx.x & 63;
    int w = threadIdx.x >> 6;
    int wr = w >> 1, wc = w & 1;
    int rg0 = blockIdx.x * 8 + wr * 4;
    const short8* Ap = (const short8*)A;
    const short8* Bp = (const short8*)B;
    f32x4 acc[4][4];
#pragma unroll
    for (int m = 0; m < 4; ++m)
#pragma unroll
        for (int n = 0; n < 4; ++n) acc[m][n] = (f32x4){0.f, 0.f, 0.f, 0.f};
#pragma unroll 2
    for (int kg = 0; kg < KG; ++kg) {
        short8 a[4], b[4];
#pragma unroll
        for (int m = 0; m < 4; ++m) {
            int rg = rg0 + m;
            rg = rg < NG ? rg : NG - 1;
            a[m] = Ap[((size_t)rg * KG + kg) * 64 + lane];
        }
#pragma unroll
        for (int n = 0; n < 4; ++n)
            b[n] = Bp[(((size_t)(kgB + kg)) * 8 + wc * 4 + n) * 64 + lane];
#pragma unroll
        for (int m = 0; m < 4; ++m)
#pragma unroll
            for (int n = 0; n < 4; ++n)
                acc[m][n] = __builtin_amdgcn_mfma_f32_16x16x32_bf16(
                    a[m], b[n], acc[m][n], 0, 0, 0);
    }
    // D layout (m89-verified): col = lane&15, row = (lane>>4)*4 + reg
    int col0 = wc * 64 + (lane & 15);
    int rbase = blockIdx.x * 128 + wr * 64 + ((lane >> 4) << 2);
#pragma unroll
    for (int m = 0; m < 4; ++m)
#pragma unroll
        for (int r = 0; r < 4; ++r) {
            int row = rbase + m * 16 + r;
            if (row < N) {
                float* op = out + ((size_t)row << 7) + col0;
                if (addend) {
                    const unsigned short* ap = addend + ((size_t)row << 7) + col0;
#pragma unroll
                    for (int n = 0; n < 4; ++n)
                        op[n * 16] =
                            __uint_as_float((unsigned int)ap[n * 16] << 16) +
                            acc[m][n][r];
                } else {
                    const float* ap = addf + ((size_t)row << 7) + col0;
#pragma unroll
                    for (int n = 0; n < 4; ++n)
                        op[n * 16] = ap[n * 16] + acc[m][n][r];
                }
            }
        }
}

extern "C" void kernel_launch(void* const* d_in, const int* in_sizes, int n_in,
                              void* d_out, int out_size, void* d_ws, size_t ws_size,
                              hipStream_t stream) {
    const float* h = (const float*)d_in[0];
    const float* W = (const float*)d_in[1];
    const int* src = (const int*)d_in[2];
    const int* dst = (const int*)d_in[3];
    float* out = (float*)d_out;

    const int N = in_sizes[0] / D;     // 100000
    const int R = 3;
    const int E = in_sizes[2] / R;     // 500000
    const int RN = R * N;
    const int NG = (N + 15) / 16;      // 6250 row groups
    const int nbE = (E + 255) / 256;

    auto al16 = [](size_t x) { return (x + 15) & ~(size_t)15; };
    size_t sz_hb = al16((size_t)(N + 1) * D * 2);   // +1 zero row
    size_t sz_Wb = al16((size_t)12 * 8 * 64 * 8 * 2);
    size_t sz_head = al16((size_t)RN * 4);
    size_t sz_chain = al16((size_t)R * E * 8);
    size_t sz_csr = al16((size_t)RN * PAD * 4);
    size_t sz_deg = al16((size_t)RN * 4);
    size_t sz_A12 = al16((size_t)NG * 12 * 512 * 2);
    size_t sz_A4 = al16((size_t)NG * 4 * 512 * 2);
    size_t baseB = sz_A12 + sz_hb + sz_Wb + sz_head + sz_chain;
    bool tierA = ws_size >= baseB + sz_csr + sz_deg;   // fused + CSR
    bool tierB = !tierA && ws_size >= baseB;           // fused + chain-walk agg
    size_t sz_A = (tierA || tierB) ? sz_A12 : sz_A4;

    char* p = (char*)d_ws;
    unsigned short* A  = (unsigned short*)p; p += sz_A;
    unsigned short* hb = (unsigned short*)p; p += sz_hb;
    unsigned short* Wb = (unsigned short*)p; p += sz_Wb;
    int*  head  = (int*)p;  p += sz_head;
    int2* chain = (int2*)p; p += sz_chain;
    int*  csr = (int*)p;    p += sz_csr;
    int*  deg = (int*)p;    p += sz_deg;

    hipMemsetAsync(head, 0xFF, (size_t)RN * 4, stream);   // head = -1
    int n8 = N * D / 8, n8tot = (N + 1) * D / 8;
    conv_h_k<<<(n8tot + 255) / 256, 256, 0, stream>>>(h, hb, n8, n8tot);
    pack_w_k<<<(12 * 8 * 64 + 255) / 256, 256, 0, stream>>>(W, Wb);
    chain_k<<<R * nbE, 256, 0, stream>>>(src, dst, head, chain, E, N, nbE);
    if (tierA)
        flat_k<<<(RN + 255) / 256, 256, 0, stream>>>(head, chain, csr, deg, RN);

    int gblk = (NG + 7) / 8;
    int useCsr = tierA ? 1 : 0;
    if (tierA || tierB) {
        agg_k<<<R * NG, 256, 0, stream>>>(hb, csr, deg, head, chain, A,
                                          N, NG, 12, 4, 0, useCsr);
        gemm_k<12><<<gblk, 256, 0, stream>>>(A, Wb, hb, nullptr, out, N, NG, 0);
    } else {
        for (int r = 0; r < R; ++r) {
            agg_k<<<NG, 256, 0, stream>>>(hb, csr, deg, head, chain, A,
                                          N, NG, 4, 0, r, 0);
            gemm_k<4><<<gblk, 256, 0, stream>>>(
                A, Wb, (r == 0) ? hb : nullptr, (r == 0) ? nullptr : out, out,
                N, NG, r * 4);
        }
    }
}

// Round 7
// 207.206 us; speedup vs baseline: 1.2644x; 1.1918x over previous
//
#include <hip/hip_runtime.h>

#define D 128
#define TN 64      // nodes per block
#define NR 3       // relations

typedef short short8 __attribute__((ext_vector_type(8)));
typedef float f32x4 __attribute__((ext_vector_type(4)));

// round-to-nearest-even f32 -> bf16 bits
__device__ __forceinline__ unsigned int f2bf(float x) {
    unsigned int u = __float_as_uint(x);
    return (u + 0x7fffu + ((u >> 16) & 1u)) >> 16;
}

// ---------------- h f32 -> bf16 (row-major [N][128]) + zero row at N ---------
__global__ __launch_bounds__(256) void conv_h_k(const float* __restrict__ h,
                                                unsigned short* __restrict__ hb,
                                                int n8, int n8tot) {
    int i = blockIdx.x * 256 + threadIdx.x;
    if (i >= n8tot) return;
    if (i >= n8) {  // zero row (gather sink)
        ((uint4*)hb)[i] = make_uint4(0u, 0u, 0u, 0u);
        return;
    }
    const float4* hp = (const float4*)h;
    float4 v0 = hp[2 * i + 0], v1 = hp[2 * i + 1];
    uint4 o;
    o.x = f2bf(v0.x) | (f2bf(v0.y) << 16);
    o.y = f2bf(v0.z) | (f2bf(v0.w) << 16);
    o.z = f2bf(v1.x) | (f2bf(v1.y) << 16);
    o.w = f2bf(v1.z) | (f2bf(v1.w) << 16);
    ((uint4*)hb)[i] = o;
}

// ---------------- W pack: B-fragment order [12][8][64][8] bf16 ---------------
// B[k][col]: lane l supplies k = kg*32 + (l>>4)*8 + j, col = cg*16 + (l&15).
__global__ void pack_w_k(const float* __restrict__ W,
                         unsigned short* __restrict__ Wb) {
    int t = blockIdx.x * 256 + threadIdx.x;
    if (t >= 12 * 8 * 64) return;
    int lane = t & 63, cg = (t >> 6) & 7, kg = t >> 9;
    int col = cg * 16 + (lane & 15);
    int r = kg >> 2;
    int klocal = (kg & 3) * 32 + (lane >> 4) * 8;
    const float* Ws = W + ((size_t)r * D + klocal) * D + col;
    uint4 o;
    o.x = f2bf(Ws[0 * D]) | (f2bf(Ws[1 * D]) << 16);
    o.y = f2bf(Ws[2 * D]) | (f2bf(Ws[3 * D]) << 16);
    o.z = f2bf(Ws[4 * D]) | (f2bf(Ws[5 * D]) << 16);
    o.w = f2bf(Ws[6 * D]) | (f2bf(Ws[7 * D]) << 16);
    ((uint4*)Wb)[t] = o;
}

// ---------------- chain build: one pass, coalesced 8B writes -----------------
__global__ void chain_k(const int* __restrict__ src, const int* __restrict__ dst,
                        int* __restrict__ head, int2* __restrict__ chain,
                        int E, int N, int nbE) {
    int r = blockIdx.x / nbE;
    int i = (blockIdx.x - r * nbE) * 256 + threadIdx.x;
    if (i >= E) return;
    size_t gi = (size_t)r * E + i;
    int d = dst[gi];
    int s = src[gi];
    int old = atomicExch(&head[r * N + d], (int)gi);
    chain[gi] = make_int2(s, old);
}

// ---------------- fused: walk -> gather (LDS A tile) -> MFMA -> epilogue -----
// Block = 512 threads, 64 output rows, K = 384 (3 relations x 128).
// LDS: A tile fragment-packed [4 rowgrp][12 kg][64 lane][8 bf16] = 48 KB,
//      idx[3][16][64] = 12 KB, degs/ovfs = 1.5 KB. Total ~63 KB.
__global__ __launch_bounds__(512, 4) void fused_k(
    const unsigned short* __restrict__ hb, const int* __restrict__ head,
    const int2* __restrict__ chain, const unsigned short* __restrict__ Wb,
    float* __restrict__ out, int N) {
    __shared__ uint4 Ald[4 * 12 * 64];      // 48 KB
    __shared__ int idxs[NR][16][TN];        // 12 KB
    __shared__ int degs[NR][TN];
    __shared__ int ovfs[NR][TN];

    const int tid = threadIdx.x;
    const int blk = blockIdx.x;

    // ---- phase W: walk chains into LDS (192 walkers) ----
    if (tid < NR * TN) {
        int r = tid / TN, nl = tid - r * TN;
        int n = blk * TN + nl;
        if (n >= N) n = N - 1;
        int e = head[r * N + n];
        int d = 0, ov = -1;
        while (e >= 0) {
            if (d == 16) ov = e;            // 17th edge onward: overflow walk
            int2 ce = chain[e];
            if (d < 16) idxs[r][d][nl] = ce.x;
            ++d;
            e = ce.y;
        }
        degs[r][nl] = d;
        ovfs[r][nl] = ov;
    }
    __syncthreads();

    // ---- phase G: gather-mean, write A fragments to LDS ----
    const int lane = tid & 63;
    const int kgl = (tid >> 6) & 3;
    const int sub = tid >> 8;                   // 0..1
    const int c = kgl * 32 + ((lane >> 4) << 3);  // feature offset (elements)

#define ACC8(u)                                                              \
    {                                                                        \
        a0 += __uint_as_float((u).x << 16);                                  \
        a1 += __uint_as_float((u).x & 0xffff0000u);                          \
        a2 += __uint_as_float((u).y << 16);                                  \
        a3 += __uint_as_float((u).y & 0xffff0000u);                          \
        a4 += __uint_as_float((u).z << 16);                                  \
        a5 += __uint_as_float((u).z & 0xffff0000u);                          \
        a6 += __uint_as_float((u).w << 16);                                  \
        a7 += __uint_as_float((u).w & 0xffff0000u);                          \
    }
#define GLD(s) (*(const uint4*)(hb + ((size_t)(s) << 7) + c))

#pragma unroll
    for (int pass = 0; pass < 2; ++pass) {
        int rg = pass * 2 + sub;                // rowgrp 0..3
        int nl = rg * 16 + (lane & 15);         // local node 0..63
        for (int r = 0; r < NR; ++r) {
            int cnt = degs[r][nl];
            float a0 = 0, a1 = 0, a2 = 0, a3 = 0, a4 = 0, a5 = 0, a6 = 0,
                  a7 = 0;
            if (cnt > 0) {
                int s0 = idxs[r][0][nl];
                int s1 = (1 < cnt) ? idxs[r][1][nl] : N;
                int s2 = (2 < cnt) ? idxs[r][2][nl] : N;
                int s3 = (3 < cnt) ? idxs[r][3][nl] : N;
                int s4 = (4 < cnt) ? idxs[r][4][nl] : N;
                int s5 = (5 < cnt) ? idxs[r][5][nl] : N;
                int s6 = (6 < cnt) ? idxs[r][6][nl] : N;
                int s7 = (7 < cnt) ? idxs[r][7][nl] : N;
                uint4 u0 = GLD(s0), u1 = GLD(s1), u2 = GLD(s2), u3 = GLD(s3);
                uint4 u4 = GLD(s4), u5 = GLD(s5), u6 = GLD(s6), u7 = GLD(s7);
                ACC8(u0); ACC8(u1); ACC8(u2); ACC8(u3);
                ACC8(u4); ACC8(u5); ACC8(u6); ACC8(u7);
            }
            if (cnt > 8) {
                int s0 = idxs[r][8][nl];
                int s1 = (9 < cnt) ? idxs[r][9][nl] : N;
                int s2 = (10 < cnt) ? idxs[r][10][nl] : N;
                int s3 = (11 < cnt) ? idxs[r][11][nl] : N;
                int s4 = (12 < cnt) ? idxs[r][12][nl] : N;
                int s5 = (13 < cnt) ? idxs[r][13][nl] : N;
                int s6 = (14 < cnt) ? idxs[r][14][nl] : N;
                int s7 = (15 < cnt) ? idxs[r][15][nl] : N;
                uint4 u0 = GLD(s0), u1 = GLD(s1), u2 = GLD(s2), u3 = GLD(s3);
                uint4 u4 = GLD(s4), u5 = GLD(s5), u6 = GLD(s6), u7 = GLD(s7);
                ACC8(u0); ACC8(u1); ACC8(u2); ACC8(u3);
                ACC8(u4); ACC8(u5); ACC8(u6); ACC8(u7);
            }
            if (cnt > 16) {  // rare overflow: continue the chain walk
                int e = ovfs[r][nl];
                while (e >= 0) {
                    int2 ce = chain[e];
                    uint4 u = GLD(ce.x);
                    ACC8(u);
                    e = ce.y;
                }
            }
            float sc = 1.0f / (3.0f * fmaxf((float)cnt, 1.0f));
            uint4 o;
            o.x = f2bf(a0 * sc) | (f2bf(a1 * sc) << 16);
            o.y = f2bf(a2 * sc) | (f2bf(a3 * sc) << 16);
            o.z = f2bf(a4 * sc) | (f2bf(a5 * sc) << 16);
            o.w = f2bf(a6 * sc) | (f2bf(a7 * sc) << 16);
            Ald[((rg * 12 + r * 4 + kgl) << 6) + lane] = o;
        }
    }
#undef ACC8
#undef GLD
    __syncthreads();

    // ---- phase M: MFMA from LDS A + global B ----
    const int w = tid >> 6;                 // 0..7
    const int wr = w >> 2, wc = w & 3;      // 2 x 4 wave grid (32-row x 32-col)
    const short8* Ap = (const short8*)Ald;
    const short8* Bp = (const short8*)Wb;
    f32x4 acc[2][2];
#pragma unroll
    for (int m = 0; m < 2; ++m)
#pragma unroll
        for (int n = 0; n < 2; ++n) acc[m][n] = (f32x4){0.f, 0.f, 0.f, 0.f};
#pragma unroll 4
    for (int kg = 0; kg < 12; ++kg) {
        short8 a[2], b[2];
#pragma unroll
        for (int m = 0; m < 2; ++m)
            a[m] = Ap[(((wr * 2 + m) * 12 + kg) << 6) + lane];
#pragma unroll
        for (int n = 0; n < 2; ++n)
            b[n] = Bp[(((size_t)kg * 8) + wc * 2 + n) * 64 + lane];
#pragma unroll
        for (int m = 0; m < 2; ++m)
#pragma unroll
            for (int n = 0; n < 2; ++n)
                acc[m][n] = __builtin_amdgcn_mfma_f32_16x16x32_bf16(
                    a[m], b[n], acc[m][n], 0, 0, 0);
    }
    // epilogue: out = bf2f(hb) + acc. D layout: col=lane&15, row=(lane>>4)*4+reg
    int col0 = wc * 32 + (lane & 15);
    int rloc = wr * 32 + ((lane >> 4) << 2);
#pragma unroll
    for (int m = 0; m < 2; ++m)
#pragma unroll
        for (int rr = 0; rr < 4; ++rr) {
            int row = blk * TN + rloc + m * 16 + rr;
            if (row < N) {
                const unsigned short* ap = hb + ((size_t)row << 7) + col0;
                float* op = out + ((size_t)row << 7) + col0;
#pragma unroll
                for (int n = 0; n < 2; ++n)
                    op[n * 16] =
                        __uint_as_float((unsigned int)ap[n * 16] << 16) +
                        acc[m][n][rr];
            }
        }
}

extern "C" void kernel_launch(void* const* d_in, const int* in_sizes, int n_in,
                              void* d_out, int out_size, void* d_ws, size_t ws_size,
                              hipStream_t stream) {
    const float* h = (const float*)d_in[0];
    const float* W = (const float*)d_in[1];
    const int* src = (const int*)d_in[2];
    const int* dst = (const int*)d_in[3];
    float* out = (float*)d_out;

    const int N = in_sizes[0] / D;     // 100000
    const int E = in_sizes[2] / NR;    // 500000
    const int RN = NR * N;
    const int nbE = (E + 255) / 256;

    auto al16 = [](size_t x) { return (x + 15) & ~(size_t)15; };
    size_t sz_hb = al16((size_t)(N + 1) * D * 2);   // +1 zero row
    size_t sz_Wb = al16((size_t)12 * 8 * 64 * 8 * 2);
    size_t sz_head = al16((size_t)RN * 4);

    char* p = (char*)d_ws;
    unsigned short* hb = (unsigned short*)p; p += sz_hb;
    unsigned short* Wb = (unsigned short*)p; p += sz_Wb;
    int*  head  = (int*)p;  p += sz_head;
    int2* chain = (int2*)p;

    hipMemsetAsync(head, 0xFF, (size_t)RN * 4, stream);   // head = -1
    int n8 = N * D / 8, n8tot = (N + 1) * D / 8;
    conv_h_k<<<(n8tot + 255) / 256, 256, 0, stream>>>(h, hb, n8, n8tot);
    pack_w_k<<<(12 * 8 * 64 + 255) / 256, 256, 0, stream>>>(W, Wb);
    chain_k<<<NR * nbE, 256, 0, stream>>>(src, dst, head, chain, E, N, nbE);

    int nb = (N + TN - 1) / TN;
    fused_k<<<nb, 512, 0, stream>>>(hb, head, chain, Wb, out, N);
}

// Round 8
// 203.284 us; speedup vs baseline: 1.2888x; 1.0193x over previous
//
#include <hip/hip_runtime.h>

#define D 128
#define TN 64      // nodes per block
#define NR 3       // relations

typedef short short8 __attribute__((ext_vector_type(8)));
typedef float f32x4 __attribute__((ext_vector_type(4)));

// round-to-nearest-even f32 -> bf16 bits
__device__ __forceinline__ unsigned int f2bf(float x) {
    unsigned int u = __float_as_uint(x);
    return (u + 0x7fffu + ((u >> 16) & 1u)) >> 16;
}

// ---------------- h f32 -> bf16 (row-major [N][128]) + zero row at N ---------
__global__ __launch_bounds__(256) void conv_h_k(const float* __restrict__ h,
                                                unsigned short* __restrict__ hb,
                                                int n8, int n8tot) {
    int i = blockIdx.x * 256 + threadIdx.x;
    if (i >= n8tot) return;
    if (i >= n8) {  // zero row (gather sink)
        ((uint4*)hb)[i] = make_uint4(0u, 0u, 0u, 0u);
        return;
    }
    const float4* hp = (const float4*)h;
    float4 v0 = hp[2 * i + 0], v1 = hp[2 * i + 1];
    uint4 o;
    o.x = f2bf(v0.x) | (f2bf(v0.y) << 16);
    o.y = f2bf(v0.z) | (f2bf(v0.w) << 16);
    o.z = f2bf(v1.x) | (f2bf(v1.y) << 16);
    o.w = f2bf(v1.z) | (f2bf(v1.w) << 16);
    ((uint4*)hb)[i] = o;
}

// ---------------- W pack: B-fragment order [12][8][64][8] bf16 ---------------
// Wb kg index = r*4 + klocal/32; lane l supplies k = (l>>4)*8+j, col = cg*16+(l&15).
__global__ void pack_w_k(const float* __restrict__ W,
                         unsigned short* __restrict__ Wb) {
    int t = blockIdx.x * 256 + threadIdx.x;
    if (t >= 12 * 8 * 64) return;
    int lane = t & 63, cg = (t >> 6) & 7, kg = t >> 9;
    int col = cg * 16 + (lane & 15);
    int r = kg >> 2;
    int klocal = (kg & 3) * 32 + (lane >> 4) * 8;
    const float* Ws = W + ((size_t)r * D + klocal) * D + col;
    uint4 o;
    o.x = f2bf(Ws[0 * D]) | (f2bf(Ws[1 * D]) << 16);
    o.y = f2bf(Ws[2 * D]) | (f2bf(Ws[3 * D]) << 16);
    o.z = f2bf(Ws[4 * D]) | (f2bf(Ws[5 * D]) << 16);
    o.w = f2bf(Ws[6 * D]) | (f2bf(Ws[7 * D]) << 16);
    ((uint4*)Wb)[t] = o;
}

// ---------------- chain build: one pass, coalesced 8B writes -----------------
__global__ void chain_k(const int* __restrict__ src, const int* __restrict__ dst,
                        int* __restrict__ head, int2* __restrict__ chain,
                        int E, int N, int nbE) {
    int r = blockIdx.x / nbE;
    int i = (blockIdx.x - r * nbE) * 256 + threadIdx.x;
    if (i >= E) return;
    size_t gi = (size_t)r * E + i;
    int d = dst[gi];
    int s = src[gi];
    int old = atomicExch(&head[r * N + d], (int)gi);
    chain[gi] = make_int2(s, old);
}

// ---------------- fused: walk -> 2x(gather half -> MFMA half) -> epilogue ----
// Block = 512 threads, 64 output rows, K = 384 (3 rel x 128 feat).
// K split into two 64-feature halves: Ald [4 rowgrp][6 kg][64 lane] = 24 KB,
// idx[3][16][64] = 12 KB, degs/ovfs = 1.5 KB. Total ~37.6 KB -> 4 blocks/CU.
__global__ __launch_bounds__(512, 8) void fused_k(
    const unsigned short* __restrict__ hb, const int* __restrict__ head,
    const int2* __restrict__ chain, const unsigned short* __restrict__ Wb,
    float* __restrict__ out, int N) {
    __shared__ uint4 Ald[4 * 6 * 64];       // 24 KB
    __shared__ int idxs[NR][16][TN];        // 12 KB
    __shared__ int degs[NR][TN];
    __shared__ int ovfs[NR][TN];

    const int tid = threadIdx.x;
    const int blk = blockIdx.x;

    // ---- phase W: walk chains into LDS (192 walkers) ----
    if (tid < NR * TN) {
        int r = tid / TN, nl = tid - r * TN;
        int n = blk * TN + nl;
        if (n >= N) n = N - 1;
        int e = head[r * N + n];
        int d = 0, ov = -1;
        while (e >= 0) {
            if (d == 16) ov = e;            // 17th edge onward: overflow walk
            int2 ce = chain[e];
            if (d < 16) idxs[r][d][nl] = ce.x;
            ++d;
            e = ce.y;
        }
        degs[r][nl] = d;
        ovfs[r][nl] = ov;
    }
    __syncthreads();

    const int lane = tid & 63;
    const int kgl = (tid >> 6) & 1;             // k sub-block within half
    const int rg = tid >> 7;                    // rowgrp 0..3
    const int nl = rg * 16 + (lane & 15);       // local node 0..63
    const int w = tid >> 6;                     // wave 0..7
    const int wr = w >> 2, wc = w & 3;          // 2 x 4 wave grid for MFMA

    const short8* Ap = (const short8*)Ald;
    const short8* Bp = (const short8*)Wb;
    f32x4 acc[2][2];
#pragma unroll
    for (int m = 0; m < 2; ++m)
#pragma unroll
        for (int n = 0; n < 2; ++n) acc[m][n] = (f32x4){0.f, 0.f, 0.f, 0.f};

#define ACC8(u)                                                              \
    {                                                                        \
        a0 += __uint_as_float((u).x << 16);                                  \
        a1 += __uint_as_float((u).x & 0xffff0000u);                          \
        a2 += __uint_as_float((u).y << 16);                                  \
        a3 += __uint_as_float((u).y & 0xffff0000u);                          \
        a4 += __uint_as_float((u).z << 16);                                  \
        a5 += __uint_as_float((u).z & 0xffff0000u);                          \
        a6 += __uint_as_float((u).w << 16);                                  \
        a7 += __uint_as_float((u).w & 0xffff0000u);                          \
    }
#define GLD(s) (*(const uint4*)(hb + ((size_t)(s) << 7) + c))

#pragma unroll
    for (int khalf = 0; khalf < 2; ++khalf) {
        // ---- gather-mean this half's features, write A fragments to LDS ----
        const int c = khalf * 64 + kgl * 32 + ((lane >> 4) << 3);
        for (int r = 0; r < NR; ++r) {
            int cnt = degs[r][nl];
            float a0 = 0, a1 = 0, a2 = 0, a3 = 0, a4 = 0, a5 = 0, a6 = 0,
                  a7 = 0;
            if (cnt > 0) {
                int s0 = idxs[r][0][nl];
                int s1 = (1 < cnt) ? idxs[r][1][nl] : N;
                int s2 = (2 < cnt) ? idxs[r][2][nl] : N;
                int s3 = (3 < cnt) ? idxs[r][3][nl] : N;
                int s4 = (4 < cnt) ? idxs[r][4][nl] : N;
                int s5 = (5 < cnt) ? idxs[r][5][nl] : N;
                int s6 = (6 < cnt) ? idxs[r][6][nl] : N;
                int s7 = (7 < cnt) ? idxs[r][7][nl] : N;
                uint4 u0 = GLD(s0), u1 = GLD(s1), u2 = GLD(s2), u3 = GLD(s3);
                uint4 u4 = GLD(s4), u5 = GLD(s5), u6 = GLD(s6), u7 = GLD(s7);
                ACC8(u0); ACC8(u1); ACC8(u2); ACC8(u3);
                ACC8(u4); ACC8(u5); ACC8(u6); ACC8(u7);
            }
            if (cnt > 8) {
                int s0 = idxs[r][8][nl];
                int s1 = (9 < cnt) ? idxs[r][9][nl] : N;
                int s2 = (10 < cnt) ? idxs[r][10][nl] : N;
                int s3 = (11 < cnt) ? idxs[r][11][nl] : N;
                int s4 = (12 < cnt) ? idxs[r][12][nl] : N;
                int s5 = (13 < cnt) ? idxs[r][13][nl] : N;
                int s6 = (14 < cnt) ? idxs[r][14][nl] : N;
                int s7 = (15 < cnt) ? idxs[r][15][nl] : N;
                uint4 u0 = GLD(s0), u1 = GLD(s1), u2 = GLD(s2), u3 = GLD(s3);
                uint4 u4 = GLD(s4), u5 = GLD(s5), u6 = GLD(s6), u7 = GLD(s7);
                ACC8(u0); ACC8(u1); ACC8(u2); ACC8(u3);
                ACC8(u4); ACC8(u5); ACC8(u6); ACC8(u7);
            }
            if (cnt > 16) {  // rare overflow: continue the chain walk
                int e = ovfs[r][nl];
                while (e >= 0) {
                    int2 ce = chain[e];
                    uint4 u = GLD(ce.x);
                    ACC8(u);
                    e = ce.y;
                }
            }
            float sc = 1.0f / (3.0f * fmaxf((float)cnt, 1.0f));
            uint4 o;
            o.x = f2bf(a0 * sc) | (f2bf(a1 * sc) << 16);
            o.y = f2bf(a2 * sc) | (f2bf(a3 * sc) << 16);
            o.z = f2bf(a4 * sc) | (f2bf(a5 * sc) << 16);
            o.w = f2bf(a6 * sc) | (f2bf(a7 * sc) << 16);
            Ald[((rg * 6 + r * 2 + kgl) << 6) + lane] = o;
        }
        __syncthreads();

        // ---- MFMA this half: 6 kg (3 rel x 2 k-blocks) ----
#pragma unroll
        for (int r = 0; r < NR; ++r)
#pragma unroll
            for (int kb = 0; kb < 2; ++kb) {
                int kgA = r * 2 + kb;                   // Ald kg index
                int kgB = r * 4 + khalf * 2 + kb;       // Wb kg index
                short8 a[2], b[2];
#pragma unroll
                for (int m = 0; m < 2; ++m)
                    a[m] = Ap[(((wr * 2 + m) * 6 + kgA) << 6) + lane];
#pragma unroll
                for (int n = 0; n < 2; ++n)
                    b[n] = Bp[(((size_t)kgB * 8) + wc * 2 + n) * 64 + lane];
#pragma unroll
                for (int m = 0; m < 2; ++m)
#pragma unroll
                    for (int n = 0; n < 2; ++n)
                        acc[m][n] = __builtin_amdgcn_mfma_f32_16x16x32_bf16(
                            a[m], b[n], acc[m][n], 0, 0, 0);
            }
        __syncthreads();
    }
#undef ACC8
#undef GLD

    // epilogue: out = bf2f(hb) + acc. D layout: col=lane&15, row=(lane>>4)*4+reg
    int col0 = wc * 32 + (lane & 15);
    int rloc = wr * 32 + ((lane >> 4) << 2);
#pragma unroll
    for (int m = 0; m < 2; ++m)
#pragma unroll
        for (int rr = 0; rr < 4; ++rr) {
            int row = blk * TN + rloc + m * 16 + rr;
            if (row < N) {
                const unsigned short* ap = hb + ((size_t)row << 7) + col0;
                float* op = out + ((size_t)row << 7) + col0;
#pragma unroll
                for (int n = 0; n < 2; ++n)
                    op[n * 16] =
                        __uint_as_float((unsigned int)ap[n * 16] << 16) +
                        acc[m][n][rr];
            }
        }
}

extern "C" void kernel_launch(void* const* d_in, const int* in_sizes, int n_in,
                              void* d_out, int out_size, void* d_ws, size_t ws_size,
                              hipStream_t stream) {
    const float* h = (const float*)d_in[0];
    const float* W = (const float*)d_in[1];
    const int* src = (const int*)d_in[2];
    const int* dst = (const int*)d_in[3];
    float* out = (float*)d_out;

    const int N = in_sizes[0] / D;     // 100000
    const int E = in_sizes[2] / NR;    // 500000
    const int RN = NR * N;
    const int nbE = (E + 255) / 256;

    auto al16 = [](size_t x) { return (x + 15) & ~(size_t)15; };
    size_t sz_hb = al16((size_t)(N + 1) * D * 2);   // +1 zero row
    size_t sz_Wb = al16((size_t)12 * 8 * 64 * 8 * 2);
    size_t sz_head = al16((size_t)RN * 4);

    char* p = (char*)d_ws;
    unsigned short* hb = (unsigned short*)p; p += sz_hb;
    unsigned short* Wb = (unsigned short*)p; p += sz_Wb;
    int*  head  = (int*)p;  p += sz_head;
    int2* chain = (int2*)p;

    hipMemsetAsync(head, 0xFF, (size_t)RN * 4, stream);   // head = -1
    int n8 = N * D / 8, n8tot = (N + 1) * D / 8;
    conv_h_k<<<(n8tot + 255) / 256, 256, 0, stream>>>(h, hb, n8, n8tot);
    pack_w_k<<<(12 * 8 * 64 + 255) / 256, 256, 0, stream>>>(W, Wb);
    chain_k<<<NR * nbE, 256, 0, stream>>>(src, dst, head, chain, E, N, nbE);

    int nb = (N + TN - 1) / TN;
    fused_k<<<nb, 512, 0, stream>>>(hb, head, chain, Wb, out, N);
}